// Round 6
// baseline (1529.271 us; speedup 1.0000x reference)
//
#include <hip/hip_runtime.h>

typedef __bf16 bf16;
typedef __bf16 bf16x8 __attribute__((ext_vector_type(8)));
typedef float  f32x4  __attribute__((ext_vector_type(4)));

#define EPSF 1e-5f

__device__ __forceinline__ float bf2f(bf16 x) { return (float)x; }
__device__ __forceinline__ bf16  f2bf(float x) { return (bf16)x; }
__device__ __forceinline__ float siluf(float x) { return x / (1.f + expf(-x)); }

// ---------------------------------------------------------------------------
// Weight prepack: W[K][N] f32 -> WT_hi[N][K], WT_lo[N][K] bf16 (hi/lo split).
// ---------------------------------------------------------------------------
struct PrepackArgs {
    const float* W[7];
    bf16* TH[7];
    bf16* TL[7];
    int K[7];
    int N[7];
};

__global__ __launch_bounds__(256) void prepack_kernel(PrepackArgs a)
{
    int s = blockIdx.y;
    int idx = blockIdx.x * 256 + threadIdx.x;
    int K = a.K[s], N = a.N[s];
    if (idx >= K * N) return;
    int k = idx / N, n = idx - k * N;
    float v = a.W[s][idx];
    bf16 hi = f2bf(v);
    a.TH[s][(size_t)n * K + k] = hi;
    a.TL[s][(size_t)n * K + k] = f2bf(v - bf2f(hi));
}

// ---------------------------------------------------------------------------
// Split-bf16 MFMA GEMM (see R4). A: hi/lo planes (AH/AL) or f32 (Af).
// B: prepacked transposed hi/lo, register-resident + prefetch.
// Epilogue modes:
//   - outZ != null (in_proj): col<512 -> z, col<1088 -> xbc (-512),
//     col>=1088 -> fused softplus/exp dt path (dtf/dAf).
//   - else generic: bias(+gelu) -> outF f32 / outB bf16 / outH+outL planes.
// ---------------------------------------------------------------------------
__global__ __launch_bounds__(256) void gemm_hl(
    const bf16* __restrict__ AH, const bf16* __restrict__ AL,
    const float* __restrict__ Af, int lda,
    const bf16* __restrict__ WTh, const bf16* __restrict__ WTl,
    const float* __restrict__ bias,
    int N, int K,
    float* __restrict__ outF, int ldF,
    bf16* __restrict__ outB, int ldB,
    bf16* __restrict__ outH, bf16* __restrict__ outL, int ldH,
    int doGelu,
    bf16* __restrict__ outZ, bf16* __restrict__ outXBC,
    const float* __restrict__ dtb, const float* __restrict__ Alog,
    float* __restrict__ dtf, float* __restrict__ dAf)
{
    __shared__ bf16 As [128][40];
    __shared__ bf16 Als[128][40];

    const int tid  = threadIdx.x;
    const int lane = tid & 63;
    const int wid  = tid >> 6;
    const int waveM = wid & 1, waveN = wid >> 1;
    const int m16 = lane & 15, quad = lane >> 4;
    const int row0 = blockIdx.x * 128;
    const int n0   = blockIdx.y * 64;

    f32x4 acc[4][2];
#pragma unroll
    for (int i = 0; i < 4; ++i)
#pragma unroll
        for (int j = 0; j < 2; ++j)
            acc[i][j] = (f32x4){0.f, 0.f, 0.f, 0.f};

    const int ar = tid >> 1, akc = (tid & 1) * 16;

    const int bn0 = min(n0 + waveN * 32 + m16,      N - 1);
    const int bn1 = min(n0 + waveN * 32 + 16 + m16, N - 1);
    const bf16* bH0p = WTh + (size_t)bn0 * K + quad * 8;
    const bf16* bH1p = WTh + (size_t)bn1 * K + quad * 8;
    const bf16* bL0p = WTl + (size_t)bn0 * K + quad * 8;
    const bf16* bL1p = WTl + (size_t)bn1 * K + quad * 8;

    bf16x8 bH[2], bL[2], bHn[2], bLn[2];
    bH[0] = *(const bf16x8*)(bH0p);
    bH[1] = *(const bf16x8*)(bH1p);
    bL[0] = *(const bf16x8*)(bL0p);
    bL[1] = *(const bf16x8*)(bL1p);

    for (int k0 = 0; k0 < K; k0 += 32) {
        // ---- stage A tile 128x32 ----
        if (AH) {
            const bf16* s0 = AH + (size_t)(row0 + ar) * lda + k0 + akc;
            const bf16* s1 = AL + (size_t)(row0 + ar) * lda + k0 + akc;
            *(uint4*)&As [ar][akc]     = *(const uint4*)s0;
            *(uint4*)&As [ar][akc + 8] = *(const uint4*)(s0 + 8);
            *(uint4*)&Als[ar][akc]     = *(const uint4*)s1;
            *(uint4*)&Als[ar][akc + 8] = *(const uint4*)(s1 + 8);
        } else {
            const float* asrc = Af + (size_t)(row0 + ar) * lda + k0 + akc;
            bf16* dh = &As [ar][akc];
            bf16* dl = &Als[ar][akc];
#pragma unroll
            for (int c = 0; c < 4; ++c) {
                float4 f = ((const float4*)asrc)[c];
#pragma unroll
                for (int e = 0; e < 4; ++e) {
                    float v = (&f.x)[e];
                    bf16 hi = f2bf(v);
                    dh[c * 4 + e] = hi;
                    dl[c * 4 + e] = f2bf(v - bf2f(hi));
                }
            }
        }
        __syncthreads();

        const bool more = (k0 + 32) < K;
        if (more) {
            int kn = k0 + 32;
            bHn[0] = *(const bf16x8*)(bH0p + kn);
            bHn[1] = *(const bf16x8*)(bH1p + kn);
            bLn[0] = *(const bf16x8*)(bL0p + kn);
            bLn[1] = *(const bf16x8*)(bL1p + kn);
        }

        bf16x8 aH[4], aL[4];
#pragma unroll
        for (int mi = 0; mi < 4; ++mi) {
            aH[mi] = *(const bf16x8*)&As [waveM * 64 + mi * 16 + m16][quad * 8];
            aL[mi] = *(const bf16x8*)&Als[waveM * 64 + mi * 16 + m16][quad * 8];
        }

#pragma unroll
        for (int mi = 0; mi < 4; ++mi)
#pragma unroll
            for (int ni = 0; ni < 2; ++ni) {
                acc[mi][ni] = __builtin_amdgcn_mfma_f32_16x16x32_bf16(
                    aH[mi], bH[ni], acc[mi][ni], 0, 0, 0);
                acc[mi][ni] = __builtin_amdgcn_mfma_f32_16x16x32_bf16(
                    aH[mi], bL[ni], acc[mi][ni], 0, 0, 0);
                acc[mi][ni] = __builtin_amdgcn_mfma_f32_16x16x32_bf16(
                    aL[mi], bH[ni], acc[mi][ni], 0, 0, 0);
            }
        __syncthreads();

        if (more) {
            bH[0] = bHn[0]; bH[1] = bHn[1];
            bL[0] = bLn[0]; bL[1] = bLn[1];
        }
    }

    // ---- epilogue ----
#pragma unroll
    for (int ni = 0; ni < 2; ++ni) {
        int col = n0 + waveN * 32 + ni * 16 + m16;
        if (col >= N) continue;
        float bv = bias ? bias[col] : 0.f;
#pragma unroll
        for (int mi = 0; mi < 4; ++mi) {
#pragma unroll
            for (int r = 0; r < 4; ++r) {
                int row = row0 + waveM * 64 + mi * 16 + quad * 4 + r;
                float v = acc[mi][ni][r] + bv;
                if (outZ) {
                    if (col < 512) {
                        outZ[(size_t)row * 512 + col] = f2bf(v);
                    } else if (col < 1088) {
                        outXBC[(size_t)row * 576 + (col - 512)] = f2bf(v);
                    } else {
                        int head = col - 1088;
                        float xx = v + dtb[head];
                        float sp = (xx > 20.f) ? xx : log1pf(expf(xx));
                        float A  = -expf(Alog[head]);
                        dtf[(size_t)row * 16 + head] = sp;
                        dAf[(size_t)row * 16 + head] = expf(sp * A);
                    }
                } else {
                    if (doGelu) v = 0.5f * v * (1.f + erff(v * 0.70710678118654752f));
                    if (outB) outB[(size_t)row * ldB + col] = f2bf(v);
                    if (outF) outF[(size_t)row * ldF + col] = v;
                    if (outH) {
                        bf16 hi = f2bf(v);
                        outH[(size_t)row * ldH + col] = hi;
                        outL[(size_t)row * ldH + col] = f2bf(v - bf2f(hi));
                    }
                }
            }
        }
    }
}

// ---------------------------------------------------------------------------
// Causal depthwise conv (K=4) + bias + silu over xBC (M x 576).
// ---------------------------------------------------------------------------
__global__ __launch_bounds__(192) void conv_kernel(
    const bf16* __restrict__ xbc,    // 32768 x 576
    const float* __restrict__ cw,    // 576 x 4
    const float* __restrict__ cb,    // 576
    float* __restrict__ xs,          // 32768 x 512
    float* __restrict__ Bc,          // 32768 x 32
    float* __restrict__ Cc)          // 32768 x 32
{
    int row = blockIdx.x;
    int ch  = blockIdx.y * 192 + threadIdx.x;   // 0..575
    int l   = row & 2047;
    float acc = cb[ch];
#pragma unroll
    for (int i = 0; i < 4; ++i) {
        int ls = l + i - 3;
        if (ls >= 0)
            acc += bf2f(xbc[(size_t)(row + i - 3) * 576 + ch]) * cw[ch * 4 + i];
    }
    float s = siluf(acc);
    if (ch < 512)      xs[(size_t)row * 512 + ch]        = s;
    else if (ch < 544) Bc[(size_t)row * 32 + (ch - 512)] = s;
    else               Cc[(size_t)row * 32 + (ch - 544)] = s;
}

// ---------------------------------------------------------------------------
// Chunked SSM scan, Q=128, 16 chunks per (b,h). 4096 blocks -> 16 waves/CU.
// ---------------------------------------------------------------------------
#define QCH   128
#define NCH   16

struct StepB  { float Bv[16]; float da, dtv, xv; };
struct StepBC { float Bv[16]; float Cv[16]; float da, dtv, xv; };

__device__ __forceinline__ void load_stepB(
    StepB& S, const float* Bc, const float* dtf, const float* dAf,
    const float* xs, size_t r, int h, int p, int nb)
{
    const float4* bp = (const float4*)(Bc + r * 32 + nb);
    *(float4*)&S.Bv[0]  = bp[0];
    *(float4*)&S.Bv[4]  = bp[1];
    *(float4*)&S.Bv[8]  = bp[2];
    *(float4*)&S.Bv[12] = bp[3];
    S.da  = dAf[r * 16 + h];
    S.dtv = dtf[r * 16 + h];
    S.xv  = xs[r * 512 + h * 32 + p];
}

__device__ __forceinline__ void load_stepBC(
    StepBC& S, const float* Bc, const float* Cc, const float* dtf,
    const float* dAf, const float* xs, size_t r, int h, int p, int nb)
{
    const float4* bp = (const float4*)(Bc + r * 32 + nb);
    *(float4*)&S.Bv[0]  = bp[0];
    *(float4*)&S.Bv[4]  = bp[1];
    *(float4*)&S.Bv[8]  = bp[2];
    *(float4*)&S.Bv[12] = bp[3];
    const float4* cp = (const float4*)(Cc + r * 32 + nb);
    *(float4*)&S.Cv[0]  = cp[0];
    *(float4*)&S.Cv[4]  = cp[1];
    *(float4*)&S.Cv[8]  = cp[2];
    *(float4*)&S.Cv[12] = cp[3];
    S.da  = dAf[r * 16 + h];
    S.dtv = dtf[r * 16 + h];
    S.xv  = xs[r * 512 + h * 32 + p];
}

__global__ __launch_bounds__(64) void scan_phase1(
    const float* __restrict__ xs,
    const float* __restrict__ Bc,
    const float* __restrict__ dtf,
    const float* __restrict__ dAf,
    float* __restrict__ cs,         // 4096 x 1024
    float* __restrict__ cp)         // 4096
{
    int blk = blockIdx.x;
    int bh = blk >> 4, c = blk & (NCH - 1);
    int b = bh >> 4, h = bh & 15;
    int lane = threadIdx.x;
    int p = lane & 31, half = lane >> 5, nb = half * 16;
    float hs[16];
#pragma unroll
    for (int j = 0; j < 16; ++j) hs[j] = 0.f;
    float P = 1.f;
    size_t rb = (size_t)b * 2048 + (size_t)c * QCH;

    StepB S0, S1;
    load_stepB(S0, Bc, dtf, dAf, xs, rb, h, p, nb);

    for (int t = 0; t < QCH; t += 2) {
        load_stepB(S1, Bc, dtf, dAf, xs, rb + t + 1, h, p, nb);
        {
            float dtx = S0.dtv * S0.xv, da = S0.da;
#pragma unroll
            for (int j = 0; j < 16; ++j)
                hs[j] = fmaf(hs[j], da, dtx * S0.Bv[j]);
            P *= da;
        }
        if (t + 2 < QCH)
            load_stepB(S0, Bc, dtf, dAf, xs, rb + t + 2, h, p, nb);
        {
            float dtx = S1.dtv * S1.xv, da = S1.da;
#pragma unroll
            for (int j = 0; j < 16; ++j)
                hs[j] = fmaf(hs[j], da, dtx * S1.Bv[j]);
            P *= da;
        }
    }

    float* dst = cs + (size_t)blk * 1024 + lane * 16;
#pragma unroll
    for (int q = 0; q < 4; ++q)
        ((float4*)dst)[q] = (float4){hs[q*4], hs[q*4+1], hs[q*4+2], hs[q*4+3]};
    if (lane == 0) cp[blk] = P;
}

__global__ __launch_bounds__(64) void scan_phase2(
    float* __restrict__ cs,
    const float* __restrict__ cp)
{
    int bh = blockIdx.x;
    int lane = threadIdx.x;
    float H[16];
#pragma unroll
    for (int j = 0; j < 16; ++j) H[j] = 0.f;
    for (int c = 0; c < NCH; ++c) {
        float* base = cs + ((size_t)(bh * NCH + c)) * 1024 + lane * 16;
        float E[16];
#pragma unroll
        for (int q = 0; q < 4; ++q) {
            float4 v = ((const float4*)base)[q];
            E[q*4] = v.x; E[q*4+1] = v.y; E[q*4+2] = v.z; E[q*4+3] = v.w;
        }
        float P = cp[bh * NCH + c];
#pragma unroll
        for (int q = 0; q < 4; ++q)
            ((float4*)base)[q] = (float4){H[q*4], H[q*4+1], H[q*4+2], H[q*4+3]};
#pragma unroll
        for (int j = 0; j < 16; ++j)
            H[j] = fmaf(H[j], P, E[j]);
    }
}

__global__ __launch_bounds__(64) void scan_phase3(
    const float* __restrict__ xs,
    const float* __restrict__ Bc,
    const float* __restrict__ Cc,
    const float* __restrict__ dtf,
    const float* __restrict__ dAf,
    const float* __restrict__ Dv,
    const float* __restrict__ cs,
    bf16* __restrict__ y)
{
    int blk = blockIdx.x;
    int bh = blk >> 4, c = blk & (NCH - 1);
    int b = bh >> 4, h = bh & 15;
    int lane = threadIdx.x;
    int p = lane & 31, half = lane >> 5, nb = half * 16;
    float Dh = Dv[h];
    float hs[16];
    {
        const float* src = cs + (size_t)blk * 1024 + lane * 16;
#pragma unroll
        for (int q = 0; q < 4; ++q) {
            float4 v = ((const float4*)src)[q];
            hs[q*4] = v.x; hs[q*4+1] = v.y; hs[q*4+2] = v.z; hs[q*4+3] = v.w;
        }
    }
    size_t rb = (size_t)b * 2048 + (size_t)c * QCH;

    StepBC S0, S1;
    load_stepBC(S0, Bc, Cc, dtf, dAf, xs, rb, h, p, nb);

    for (int t = 0; t < QCH; t += 2) {
        load_stepBC(S1, Bc, Cc, dtf, dAf, xs, rb + t + 1, h, p, nb);
        {
            float dtx = S0.dtv * S0.xv, da = S0.da, yv = 0.f;
#pragma unroll
            for (int j = 0; j < 16; ++j) {
                hs[j] = fmaf(hs[j], da, dtx * S0.Bv[j]);
                yv = fmaf(hs[j], S0.Cv[j], yv);
            }
            yv += __shfl_xor(yv, 32);
            if (half == 0)
                y[(rb + t) * 512 + h * 32 + p] = f2bf(yv + Dh * S0.xv);
        }
        if (t + 2 < QCH)
            load_stepBC(S0, Bc, Cc, dtf, dAf, xs, rb + t + 2, h, p, nb);
        {
            float dtx = S1.dtv * S1.xv, da = S1.da, yv = 0.f;
#pragma unroll
            for (int j = 0; j < 16; ++j) {
                hs[j] = fmaf(hs[j], da, dtx * S1.Bv[j]);
                yv = fmaf(hs[j], S1.Cv[j], yv);
            }
            yv += __shfl_xor(yv, 32);
            if (half == 0)
                y[(rb + t + 1) * 512 + h * 32 + p] = f2bf(yv + Dh * S1.xv);
        }
    }
}

// ---------------------------------------------------------------------------
// normed = rmsnorm(y * silu(z), nw) over 512 -> hi/lo bf16 planes.
// ---------------------------------------------------------------------------
__global__ __launch_bounds__(64) void gaterms_kernel(
    const bf16* __restrict__ y,      // 32768 x 512
    const bf16* __restrict__ z,      // 32768 x 512
    const float* __restrict__ nw,    // 512
    bf16* __restrict__ outH,
    bf16* __restrict__ outL)
{
    int row = blockIdx.x, lane = threadIdx.x;
    union { uint4 u; bf16 b[8]; } yv, zv, oh, ol;
    yv.u = *(const uint4*)(y + (size_t)row * 512 + lane * 8);
    zv.u = *(const uint4*)(z + (size_t)row * 512 + lane * 8);
    float4 nv0 = *(const float4*)(nw + lane * 8);
    float4 nv1 = *(const float4*)(nw + lane * 8 + 4);
    float nvv[8] = {nv0.x, nv0.y, nv0.z, nv0.w, nv1.x, nv1.y, nv1.z, nv1.w};
    float g[8]; float ss = 0.f;
#pragma unroll
    for (int i = 0; i < 8; ++i) {
        float gate = siluf(bf2f(zv.b[i]));
        g[i] = bf2f(yv.b[i]) * gate;
        ss += g[i] * g[i];
    }
#pragma unroll
    for (int o = 1; o < 64; o <<= 1) ss += __shfl_xor(ss, o);
    float rms = rsqrtf(ss * (1.f / 512.f) + EPSF);
#pragma unroll
    for (int i = 0; i < 8; ++i) {
        float v = g[i] * rms * nvv[i];
        bf16 hi = f2bf(v);
        oh.b[i] = hi;
        ol.b[i] = f2bf(v - bf2f(hi));
    }
    *(uint4*)(outH + (size_t)row * 512 + lane * 8) = oh.u;
    *(uint4*)(outL + (size_t)row * 512 + lane * 8) = ol.u;
}

// ---------------------------------------------------------------------------
// h = rmsnorm(mo + h, w); h stored as hi/lo planes (in/out).
// ---------------------------------------------------------------------------
__global__ __launch_bounds__(64) void resrms_kernel(
    const float* __restrict__ mo,    // 32768 x 256
    bf16* __restrict__ hH,           // 32768 x 256 (in/out)
    bf16* __restrict__ hL,
    const float* __restrict__ w)
{
    int row = blockIdx.x, lane = threadIdx.x;
    float4 a = *(const float4*)(mo + (size_t)row * 256 + lane * 4);
    union { uint2 u; bf16 b[4]; } hv, lv;
    hv.u = *(const uint2*)(hH + (size_t)row * 256 + lane * 4);
    lv.u = *(const uint2*)(hL + (size_t)row * 256 + lane * 4);
    float s[4];
    s[0] = a.x + bf2f(hv.b[0]) + bf2f(lv.b[0]);
    s[1] = a.y + bf2f(hv.b[1]) + bf2f(lv.b[1]);
    s[2] = a.z + bf2f(hv.b[2]) + bf2f(lv.b[2]);
    s[3] = a.w + bf2f(hv.b[3]) + bf2f(lv.b[3]);
    float ss = s[0]*s[0] + s[1]*s[1] + s[2]*s[2] + s[3]*s[3];
#pragma unroll
    for (int o = 1; o < 64; o <<= 1) ss += __shfl_xor(ss, o);
    float rms = rsqrtf(ss * (1.f / 256.f) + EPSF);
    float4 wv = *(const float4*)(w + lane * 4);
    float o[4] = {s[0]*rms*wv.x, s[1]*rms*wv.y, s[2]*rms*wv.z, s[3]*rms*wv.w};
    union { uint2 u; bf16 b[4]; } oh, ol;
#pragma unroll
    for (int i = 0; i < 4; ++i) {
        bf16 hi = f2bf(o[i]);
        oh.b[i] = hi;
        ol.b[i] = f2bf(o[i] - bf2f(hi));
    }
    *(uint2*)(hH + (size_t)row * 256 + lane * 4) = oh.u;
    *(uint2*)(hL + (size_t)row * 256 + lane * 4) = ol.u;
}

// ---------------------------------------------------------------------------
// layernorm over 256. Input: f32 (xF) or planes (xHi/xLo). Output planes
// and/or f32. One wave per row, 4/lane.
// ---------------------------------------------------------------------------
__global__ __launch_bounds__(64) void ln_kernel(
    const float* __restrict__ xF,
    const bf16* __restrict__ xHi, const bf16* __restrict__ xLo,
    const float* __restrict__ w,
    const float* __restrict__ b,
    bf16* __restrict__ outH,
    bf16* __restrict__ outL,
    float* __restrict__ outF)
{
    int row = blockIdx.x, lane = threadIdx.x;
    float v0, v1, v2, v3;
    if (xF) {
        float4 v = *(const float4*)(xF + (size_t)row * 256 + lane * 4);
        v0 = v.x; v1 = v.y; v2 = v.z; v3 = v.w;
    } else {
        union { uint2 u; bf16 b[4]; } hv, lv;
        hv.u = *(const uint2*)(xHi + (size_t)row * 256 + lane * 4);
        lv.u = *(const uint2*)(xLo + (size_t)row * 256 + lane * 4);
        v0 = bf2f(hv.b[0]) + bf2f(lv.b[0]);
        v1 = bf2f(hv.b[1]) + bf2f(lv.b[1]);
        v2 = bf2f(hv.b[2]) + bf2f(lv.b[2]);
        v3 = bf2f(hv.b[3]) + bf2f(lv.b[3]);
    }
    float sum = v0 + v1 + v2 + v3;
    float sq  = v0*v0 + v1*v1 + v2*v2 + v3*v3;
#pragma unroll
    for (int o = 1; o < 64; o <<= 1) { sum += __shfl_xor(sum, o); sq += __shfl_xor(sq, o); }
    float m  = sum * (1.f / 256.f);
    float var = sq * (1.f / 256.f) - m * m;
    float is = rsqrtf(var + EPSF);
    float4 wv = *(const float4*)(w + lane * 4);
    float4 bv = *(const float4*)(b + lane * 4);
    float o0 = (v0 - m) * is * wv.x + bv.x;
    float o1 = (v1 - m) * is * wv.y + bv.y;
    float o2 = (v2 - m) * is * wv.z + bv.z;
    float o3 = (v3 - m) * is * wv.w + bv.w;
    if (outH) {
        union { uint2 u; bf16 bb[4]; } oh, ol;
        float o[4] = {o0, o1, o2, o3};
#pragma unroll
        for (int i = 0; i < 4; ++i) {
            bf16 hi = f2bf(o[i]);
            oh.bb[i] = hi;
            ol.bb[i] = f2bf(o[i] - bf2f(hi));
        }
        *(uint2*)(outH + (size_t)row * 256 + lane * 4) = oh.u;
        *(uint2*)(outL + (size_t)row * 256 + lane * 4) = ol.u;
    }
    if (outF)
        *(float4*)(outF + (size_t)row * 256 + lane * 4) = (float4){o0, o1, o2, o3};
}

// ---------------------------------------------------------------------------
extern "C" void kernel_launch(void* const* d_in, const int* in_sizes, int n_in,
                              void* d_out, int out_size, void* d_ws, size_t ws_size,
                              hipStream_t stream)
{
    const float* x      = (const float*)d_in[0];
    const float* ip_w   = (const float*)d_in[1];
    const float* ip_b   = (const float*)d_in[2];
    const float* m_inw  = (const float*)d_in[3];
    const float* m_inb  = (const float*)d_in[4];
    const float* m_convw= (const float*)d_in[5];
    const float* m_convb= (const float*)d_in[6];
    const float* m_dtb  = (const float*)d_in[7];
    const float* m_Alog = (const float*)d_in[8];
    const float* m_D    = (const float*)d_in[9];
    const float* m_nw   = (const float*)d_in[10];
    const float* m_outw = (const float*)d_in[11];
    const float* m_outb = (const float*)d_in[12];
    const float* rms_w  = (const float*)d_in[13];
    const float* ln1_w  = (const float*)d_in[14];
    const float* ln1_b  = (const float*)d_in[15];
    const float* w1     = (const float*)d_in[16];
    const float* b1     = (const float*)d_in[17];
    const float* w2     = (const float*)d_in[18];
    const float* b2     = (const float*)d_in[19];
    const float* ln2_w  = (const float*)d_in[20];
    const float* ln2_b  = (const float*)d_in[21];

    const int M = 32768;
    char* wsb = (char*)d_ws;
    size_t off = 0;
    auto alloc = [&](size_t bytes) {
        void* p = wsb + off;
        off += (bytes + 255) & ~(size_t)255;
        return p;
    };
    // ---- regions (~224 MB) ----
    bf16*  zb   = (bf16*) alloc((size_t)M * 512 * 2);  // z; later gH (MLP)
    bf16*  xbc  = (bf16*) alloc((size_t)M * 576 * 2);  // xBC; -> cs; -> mo f32; -> gL
    bf16*  hH   = (bf16*) alloc((size_t)M * 256 * 2);  // residual hi plane
    bf16*  hL   = (bf16*) alloc((size_t)M * 256 * 2);  // residual lo plane
    float* U1   = (float*)alloc((size_t)M * 512 * 4);  // xs f32 -> normed planes -> tb planes
    float* Bc   = (float*)alloc((size_t)M * 32 * 4);
    float* Cc   = (float*)alloc((size_t)M * 32 * 4);
    float* dtf  = (float*)alloc((size_t)M * 16 * 4);
    float* dAf  = (float*)alloc((size_t)M * 16 * 4);
    bf16*  ybuf = (bf16*) alloc((size_t)M * 512 * 2);  // y bf16 -> ubuf f32
    float* cpb  = (float*)alloc((size_t)4096 * 4);
    // prepacked weights
    bf16* ipTH   = (bf16*)alloc(262144 * 2);
    bf16* ipTL   = (bf16*)alloc(262144 * 2);
    bf16* inwTH0 = (bf16*)alloc(282624 * 2);
    bf16* inwTL0 = (bf16*)alloc(282624 * 2);
    bf16* inwTH1 = (bf16*)alloc(282624 * 2);
    bf16* inwTL1 = (bf16*)alloc(282624 * 2);
    bf16* outwTH0= (bf16*)alloc(131072 * 2);
    bf16* outwTL0= (bf16*)alloc(131072 * 2);
    bf16* outwTH1= (bf16*)alloc(131072 * 2);
    bf16* outwTL1= (bf16*)alloc(131072 * 2);
    bf16* w1TH   = (bf16*)alloc(131072 * 2);
    bf16* w1TL   = (bf16*)alloc(131072 * 2);
    bf16* w2TH   = (bf16*)alloc(131072 * 2);
    bf16* w2TL   = (bf16*)alloc(131072 * 2);
    (void)ws_size; (void)in_sizes; (void)n_in; (void)out_size;

    float* xs      = U1;
    bf16*  normedH = (bf16*)U1;
    bf16*  normedL = normedH + (size_t)M * 512;
    bf16*  tbH     = (bf16*)U1;
    bf16*  tbL     = tbH + (size_t)M * 256;
    float* cs      = (float*)xbc;      // 16.8 MB, xBC dead after conv
    float* mo      = (float*)xbc;      // 33.5 MB, cs dead after phase3
    bf16*  gH      = zb;               // MLP hidden planes
    bf16*  gL      = xbc;
    float* ubuf    = (float*)ybuf;

    // ---- prepack all weights ----
    PrepackArgs pa;
    pa.W[0] = ip_w;               pa.TH[0] = ipTH;    pa.TL[0] = ipTL;    pa.K[0] = 1024; pa.N[0] = 256;
    pa.W[1] = m_inw;              pa.TH[1] = inwTH0;  pa.TL[1] = inwTL0;  pa.K[1] = 256;  pa.N[1] = 1104;
    pa.W[2] = m_inw + 256*1104;   pa.TH[2] = inwTH1;  pa.TL[2] = inwTL1;  pa.K[2] = 256;  pa.N[2] = 1104;
    pa.W[3] = m_outw;             pa.TH[3] = outwTH0; pa.TL[3] = outwTL0; pa.K[3] = 512;  pa.N[3] = 256;
    pa.W[4] = m_outw + 512*256;   pa.TH[4] = outwTH1; pa.TL[4] = outwTL1; pa.K[4] = 512;  pa.N[4] = 256;
    pa.W[5] = w1;                 pa.TH[5] = w1TH;    pa.TL[5] = w1TL;    pa.K[5] = 256;  pa.N[5] = 512;
    pa.W[6] = w2;                 pa.TH[6] = w2TH;    pa.TL[6] = w2TL;    pa.K[6] = 512;  pa.N[6] = 256;
    prepack_kernel<<<dim3(1104, 7), 256, 0, stream>>>(pa);

    dim3 blk(256);

    // G1: h = x @ ip_w + ip_b -> hi/lo planes
    gemm_hl<<<dim3(256, 4), blk, 0, stream>>>(
        nullptr, nullptr, x, 1024, ipTH, ipTL, ip_b, 256, 1024,
        nullptr, 0, nullptr, 0, hH, hL, 256, 0,
        nullptr, nullptr, nullptr, nullptr, nullptr, nullptr);

    for (int L = 0; L < 2; ++L) {
        const bf16* inwTH = L ? inwTH1 : inwTH0;
        const bf16* inwTL = L ? inwTL1 : inwTL0;
        const bf16* outwTH= L ? outwTH1 : outwTH0;
        const bf16* outwTL= L ? outwTL1 : outwTL0;
        const float* inb = m_inb  + (size_t)L * 1104;
        const float* cw  = m_convw+ (size_t)L * 576 * 4;
        const float* cb  = m_convb+ (size_t)L * 576;
        const float* dtb = m_dtb  + L * 16;
        const float* Al  = m_Alog + L * 16;
        const float* Dv  = m_D    + L * 16;
        const float* nw  = m_nw   + (size_t)L * 512;
        const float* ob  = m_outb + (size_t)L * 256;
        const float* rw  = rms_w  + (size_t)L * 256;

        // in_proj from h planes; split outputs z / xBC / fused-dt
        gemm_hl<<<dim3(256, 18), blk, 0, stream>>>(
            hH, hL, nullptr, 256, inwTH, inwTL, inb, 1104, 256,
            nullptr, 0, nullptr, 0, nullptr, nullptr, 0, 0,
            zb, xbc, dtb, Al, dtf, dAf);
        conv_kernel<<<dim3(M, 3), 192, 0, stream>>>(xbc, cw, cb, xs, Bc, Cc);
        scan_phase1<<<4096, 64, 0, stream>>>(xs, Bc, dtf, dAf, cs, cpb);
        scan_phase2<<<256, 64, 0, stream>>>(cs, cpb);
        scan_phase3<<<4096, 64, 0, stream>>>(xs, Bc, Cc, dtf, dAf, Dv, cs, ybuf);
        gaterms_kernel<<<M, 64, 0, stream>>>(ybuf, zb, nw, normedH, normedL);
        gemm_hl<<<dim3(256, 4), blk, 0, stream>>>(
            normedH, normedL, nullptr, 512, outwTH, outwTL, ob, 256, 512,
            mo, 256, nullptr, 0, nullptr, nullptr, 0, 0,
            nullptr, nullptr, nullptr, nullptr, nullptr, nullptr);
        resrms_kernel<<<M, 64, 0, stream>>>(mo, hH, hL, rw);
    }

    // MLP head
    ln_kernel<<<M, 64, 0, stream>>>(nullptr, hH, hL, ln1_w, ln1_b, tbH, tbL, nullptr);
    gemm_hl<<<dim3(256, 8), blk, 0, stream>>>(
        tbH, tbL, nullptr, 256, w1TH, w1TL, b1, 512, 256,
        nullptr, 0, nullptr, 0, gH, gL, 512, 1,
        nullptr, nullptr, nullptr, nullptr, nullptr, nullptr);
    gemm_hl<<<dim3(256, 4), blk, 0, stream>>>(
        gH, gL, nullptr, 512, w2TH, w2TL, b2, 256, 512,
        ubuf, 256, nullptr, 0, nullptr, nullptr, 0, 0,
        nullptr, nullptr, nullptr, nullptr, nullptr, nullptr);
    ln_kernel<<<M, 64, 0, stream>>>(ubuf, nullptr, nullptr, ln2_w, ln2_b,
                                    nullptr, nullptr, (float*)d_out);
}